// Round 4
// baseline (646.920 us; speedup 1.0000x reference)
//
#include <hip/hip_runtime.h>

#define OBS_T 20
#define HID 128
#define NGATE 512
#define MB 16          // batch rows per block
#define HSTR 136       // hbuf row stride in bf16 (272B = 17*16B, odd multiple of 16B)

typedef __bf16 bf16x8 __attribute__((ext_vector_type(8)));
typedef __bf16 bf16x4 __attribute__((ext_vector_type(4)));
typedef float f32x4 __attribute__((ext_vector_type(4)));

__device__ __forceinline__ float fast_rcp(float x) { return __builtin_amdgcn_rcpf(x); }
__device__ __forceinline__ float sigm(float x) { return fast_rcp(1.0f + __expf(-x)); }
__device__ __forceinline__ float tanh_f(float x) {
  return 1.0f - 2.0f * fast_rcp(1.0f + __expf(2.0f * x));
}

// ---- prep 1: fold embedding into rank-2 + bias, gate-major permutation ----
// gate row r = q*128 + j (torch order i,f,g,o). np = (j>>4)*64 + q*16 + (j&15)
__global__ void prep_vec(const float* __restrict__ W_emb, const float* __restrict__ b_emb,
                         const float* __restrict__ W_ih, const float* __restrict__ b_ih,
                         const float* __restrict__ b_hh,
                         float* __restrict__ biasp, float* __restrict__ wx0p,
                         float* __restrict__ wx1p) {
  int r = blockIdx.x * blockDim.x + threadIdx.x;
  if (r >= NGATE) return;
  float s0 = 0.f, s1 = 0.f, sb = 0.f;
  for (int d = 0; d < 64; ++d) {
    float w = W_ih[r * 64 + d];
    s0 += w * W_emb[d * 2 + 0];
    s1 += w * W_emb[d * 2 + 1];
    sb += w * b_emb[d];
  }
  int q = r >> 7, j = r & 127;
  int np = (j >> 4) * 64 + q * 16 + (j & 15);
  biasp[np] = b_ih[r] + b_hh[r] + sb;
  wx0p[np] = s0;
  wx1p[np] = s1;
}

// ---- prep 2: W_hh -> bf16 B-fragments, gate-major frag order ----
// frag f = w*16 + q*4 + ks ; elem = (f*64 + lane)*8 + jj
// col n -> unit j = w*16 + (lane&15), gate q => r = q*128 + w*16 + cn
// k = ks*32 + (lane>>4)*8 + jj
__global__ void prep_wp(const float* __restrict__ W_hh, __bf16* __restrict__ Wp) {
  int tid = blockIdx.x * blockDim.x + threadIdx.x;  // 0..65535
  int jj = tid & 7;
  int lane = (tid >> 3) & 63;
  int frag = tid >> 9;  // 0..127
  int ks = frag & 3;
  int q = (frag >> 2) & 3;
  int w = frag >> 4;
  int cn = lane & 15, quad = lane >> 4;
  int r = q * 128 + w * 16 + cn;
  int k = ks * 32 + quad * 8 + jj;
  Wp[tid] = (__bf16)W_hh[r * 128 + k];
}

// ---- main fused LSTM: 8 waves/block, wave w = all 4 gates of units [16w,16w+16) ----
__global__ __launch_bounds__(512, 4) void lstm_fused(
    const float* __restrict__ obs, const float* __restrict__ h0,
    const float* __restrict__ c0, const __bf16* __restrict__ Wp,
    const float* __restrict__ biasp, const float* __restrict__ wx0p,
    const float* __restrict__ wx1p, float* __restrict__ out, int batch) {
  __shared__ __align__(16) __bf16 hbuf[2][MB][HSTR];
  __shared__ __align__(16) float obs_s[OBS_T][MB][2];

  const int tid = threadIdx.x;
  const int lane = tid & 63;
  const int wv = tid >> 6;
  const int cn = lane & 15;
  const int quad = lane >> 4;
  const int bbase = blockIdx.x * MB;
  const int junit = wv * 16 + cn;

  // stage obs tile: [20][16][2] fp32 = 160 float4
  if (tid < OBS_T * MB * 2 / 4) {
    const int t = tid >> 3, f4 = tid & 7;
    ((float4*)obs_s)[tid] = ((const float4*)obs)[(t * batch + bbase) / 2 + f4];
  }
  // stage h0 tile fp32 -> bf16 LDS: 16 rows x 32 float4 = 512, one per thread
  {
    int row = tid >> 5, c4 = tid & 31;
    float4 v = ((const float4*)h0)[(bbase + row) * 32 + c4];
    bf16x4 b;
    b.x = (__bf16)v.x; b.y = (__bf16)v.y; b.z = (__bf16)v.z; b.w = (__bf16)v.w;
    *(bf16x4*)&hbuf[0][row][c4 * 4] = b;
  }

  // persistent B fragments: 4 ksteps x 4 gates x 16B = 64 regs (AGPR side)
  bf16x8 Bf[4][4];
  {
    const bf16x8* wp8 = (const bf16x8*)Wp;
#pragma unroll
    for (int q = 0; q < 4; ++q)
#pragma unroll
      for (int ks = 0; ks < 4; ++ks)
        Bf[ks][q] = wp8[(wv * 16 + q * 4 + ks) * 64 + lane];
  }

  float bias_v[4], wx0_v[4], wx1_v[4];
#pragma unroll
  for (int q = 0; q < 4; ++q) {
    int n = wv * 64 + q * 16 + cn;
    bias_v[q] = biasp[n];
    wx0_v[q] = wx0p[n];
    wx1_v[q] = wx1p[n];
  }

  // c state: lane owns rows m = quad*4+r of unit junit, fp32
  float cc[4];
#pragma unroll
  for (int r = 0; r < 4; ++r)
    cc[r] = c0[(bbase + quad * 4 + r) * HID + junit];

  __syncthreads();

  int cur = 0;
#pragma unroll 1
  for (int t = 0; t < OBS_T - 1; ++t) {
    // acc init = bias + rank-2 folded embedding (fp32): obs via transient b64 reads
    f32x4 acc[4];
#pragma unroll
    for (int r = 0; r < 4; ++r) {
      float2 ob = *(const float2*)&obs_s[t][quad * 4 + r][0];
#pragma unroll
      for (int q = 0; q < 4; ++q)
        acc[q][r] = fmaf(ob.y, wx1_v[q], fmaf(ob.x, wx0_v[q], bias_v[q]));
    }

    // gates += h @ W_hh^T  (16 MFMAs), A loaded per-kstep to cap liveness
#pragma unroll
    for (int ks = 0; ks < 4; ++ks) {
      bf16x8 Av = *(const bf16x8*)&hbuf[cur][cn][ks * 32 + quad * 8];
#pragma unroll
      for (int q = 0; q < 4; ++q)
        acc[q] = __builtin_amdgcn_mfma_f32_16x16x32_bf16(Av, Bf[ks][q], acc[q], 0, 0, 0);
    }

    const int nxt = cur ^ 1;
#pragma unroll
    for (int r = 0; r < 4; ++r) {
      float iv = sigm(acc[0][r]);
      float fv = sigm(acc[1][r]);
      float gv = tanh_f(acc[2][r]);
      float ov = sigm(acc[3][r]);
      float c = fmaf(fv, cc[r], iv * gv);
      cc[r] = c;
      hbuf[nxt][quad * 4 + r][junit] = (__bf16)(ov * tanh_f(c));
    }
    __syncthreads();
    cur = nxt;
  }

  // peeled final step: same compute, h goes straight to global
  {
    const int t = OBS_T - 1;
    f32x4 acc[4];
#pragma unroll
    for (int r = 0; r < 4; ++r) {
      float2 ob = *(const float2*)&obs_s[t][quad * 4 + r][0];
#pragma unroll
      for (int q = 0; q < 4; ++q)
        acc[q][r] = fmaf(ob.y, wx1_v[q], fmaf(ob.x, wx0_v[q], bias_v[q]));
    }
#pragma unroll
    for (int ks = 0; ks < 4; ++ks) {
      bf16x8 Av = *(const bf16x8*)&hbuf[cur][cn][ks * 32 + quad * 8];
#pragma unroll
      for (int q = 0; q < 4; ++q)
        acc[q] = __builtin_amdgcn_mfma_f32_16x16x32_bf16(Av, Bf[ks][q], acc[q], 0, 0, 0);
    }
#pragma unroll
    for (int r = 0; r < 4; ++r) {
      float iv = sigm(acc[0][r]);
      float fv = sigm(acc[1][r]);
      float gv = tanh_f(acc[2][r]);
      float ov = sigm(acc[3][r]);
      float c = fmaf(fv, cc[r], iv * gv);
      out[(bbase + quad * 4 + r) * HID + junit] = ov * tanh_f(c);
    }
  }
}

extern "C" void kernel_launch(void* const* d_in, const int* in_sizes, int n_in,
                              void* d_out, int out_size, void* d_ws, size_t ws_size,
                              hipStream_t stream) {
  const float* obs = (const float*)d_in[0];
  const float* h0 = (const float*)d_in[1];
  const float* c0 = (const float*)d_in[2];
  const float* W_emb = (const float*)d_in[3];
  const float* b_emb = (const float*)d_in[4];
  const float* W_ih = (const float*)d_in[5];
  const float* W_hh = (const float*)d_in[6];
  const float* b_ih = (const float*)d_in[7];
  const float* b_hh = (const float*)d_in[8];
  float* out = (float*)d_out;
  const int batch = in_sizes[1] / HID;

  __bf16* Wp = (__bf16*)d_ws;                     // 65536 bf16 = 128 KB
  float* biasp = (float*)((char*)d_ws + 131072);  // 3 x 512 f32
  float* wx0p = biasp + NGATE;
  float* wx1p = wx0p + NGATE;

  prep_vec<<<2, 256, 0, stream>>>(W_emb, b_emb, W_ih, b_ih, b_hh, biasp, wx0p, wx1p);
  prep_wp<<<256, 256, 0, stream>>>(W_hh, Wp);
  lstm_fused<<<batch / MB, 512, 0, stream>>>(obs, h0, c0, Wp, biasp, wx0p, wx1p, out, batch);
}

// Round 5
// 405.395 us; speedup vs baseline: 1.5958x; 1.5958x over previous
//
#include <hip/hip_runtime.h>

#define OBS_T 20
#define HID 128
#define NGATE 512
#define MB 32          // batch rows per block = 2 independent 16-row tiles per wave
#define HSTR 136       // hbuf row stride in bf16 (272B = 17*16B)

typedef __bf16 bf16x8 __attribute__((ext_vector_type(8)));
typedef __bf16 bf16x4 __attribute__((ext_vector_type(4)));
typedef float f32x4 __attribute__((ext_vector_type(4)));

__device__ __forceinline__ float fast_rcp(float x) { return __builtin_amdgcn_rcpf(x); }
#if __has_builtin(__builtin_amdgcn_exp2f)
__device__ __forceinline__ float exp2_hw(float x) { return __builtin_amdgcn_exp2f(x); }
#else
__device__ __forceinline__ float exp2_hw(float x) { return __expf(x * 0.69314718056f); }
#endif
#define LOG2E 1.442695041f

// ---- prep 1: fold embedding into rank-2 + bias, gate-major permutation ----
// gate row r = q*128 + j (torch order i,f,g,o). np = (j>>4)*64 + q*16 + (j&15)
__global__ void prep_vec(const float* __restrict__ W_emb, const float* __restrict__ b_emb,
                         const float* __restrict__ W_ih, const float* __restrict__ b_ih,
                         const float* __restrict__ b_hh,
                         float* __restrict__ biasp, float* __restrict__ wx0p,
                         float* __restrict__ wx1p) {
  int r = blockIdx.x * blockDim.x + threadIdx.x;
  if (r >= NGATE) return;
  float s0 = 0.f, s1 = 0.f, sb = 0.f;
  for (int d = 0; d < 64; ++d) {
    float w = W_ih[r * 64 + d];
    s0 += w * W_emb[d * 2 + 0];
    s1 += w * W_emb[d * 2 + 1];
    sb += w * b_emb[d];
  }
  int q = r >> 7, j = r & 127;
  int np = (j >> 4) * 64 + q * 16 + (j & 15);
  biasp[np] = b_ih[r] + b_hh[r] + sb;
  wx0p[np] = s0;
  wx1p[np] = s1;
}

// ---- prep 2: W_hh -> bf16 B-fragments, gate-major frag order ----
// frag f = w*16 + q*4 + ks ; elem = (f*64 + lane)*8 + jj
// col n -> unit j = w*16 + (lane&15), gate q => r = q*128 + w*16 + cn
// k = ks*32 + (lane>>4)*8 + jj
__global__ void prep_wp(const float* __restrict__ W_hh, __bf16* __restrict__ Wp) {
  int tid = blockIdx.x * blockDim.x + threadIdx.x;  // 0..65535
  int jj = tid & 7;
  int lane = (tid >> 3) & 63;
  int frag = tid >> 9;  // 0..127
  int ks = frag & 3;
  int q = (frag >> 2) & 3;
  int w = frag >> 4;
  int cn = lane & 15, quad = lane >> 4;
  int r = q * 128 + w * 16 + cn;
  int k = ks * 32 + quad * 8 + jj;
  Wp[tid] = (__bf16)W_hh[r * 128 + k];
}

// lane-local LSTM cell update using merged-rcp activations:
//   sigm(a)*tanh(b) = (1 - e^{-2b}) * rcp((1 + e^{-a})(1 + e^{-2b}))
// Safe here: |gate preact| is O(10) for this data, so no inf*0.
__device__ __forceinline__ float cell_update(float gi, float gf, float gg, float go,
                                             float& c) {
  float e_i = exp2_hw(gi * -LOG2E);
  float e_f = exp2_hw(gf * -LOG2E);
  float e_g = exp2_hw(gg * (-2.f * LOG2E));
  float e_o = exp2_hw(go * -LOG2E);
  float rf = fast_rcp(1.f + e_f);                          // sigm(f)
  float ig = (1.f - e_g) * fast_rcp((1.f + e_i) * (1.f + e_g));  // sigm(i)*tanh(g)
  c = fmaf(rf, c, ig);
  float e_c = exp2_hw(c * (-2.f * LOG2E));
  return (1.f - e_c) * fast_rcp((1.f + e_o) * (1.f + e_c));  // sigm(o)*tanh(c)
}

// ---- main fused LSTM: 8 waves/block, wave w = all 4 gates of units [16w,16w+16),
// each wave runs TWO independent 16-row batch tiles for intra-wave ILP.
// launch_bounds(512,2): 256 unified regs/wave -> guaranteed no scratch spill.
__global__ __launch_bounds__(512, 2) void lstm_fused(
    const float* __restrict__ obs, const float* __restrict__ h0,
    const float* __restrict__ c0, const __bf16* __restrict__ Wp,
    const float* __restrict__ biasp, const float* __restrict__ wx0p,
    const float* __restrict__ wx1p, float* __restrict__ out, int batch) {
  __shared__ __align__(16) __bf16 hbuf[2][MB][HSTR];
  __shared__ __align__(16) float obs_s[OBS_T][MB][2];

  const int tid = threadIdx.x;
  const int lane = tid & 63;
  const int wv = tid >> 6;
  const int cn = lane & 15;
  const int quad = lane >> 4;
  const int bbase = blockIdx.x * MB;
  const int junit = wv * 16 + cn;

  // stage obs tile: [20][32][2] fp32 = 320 float4
  if (tid < OBS_T * MB * 2 / 4) {
    const int t = tid >> 4, f4 = tid & 15;
    ((float4*)obs_s)[tid] = ((const float4*)obs)[(t * batch + bbase) / 2 + f4];
  }
  // stage h0 tile fp32 -> bf16 LDS: 32 rows x 32 float4 = 1024
#pragma unroll
  for (int it = 0; it < 2; ++it) {
    int idx = tid + it * 512;
    int row = idx >> 5, c4 = idx & 31;
    float4 v = ((const float4*)h0)[(bbase + row) * 32 + c4];
    bf16x4 b;
    b.x = (__bf16)v.x; b.y = (__bf16)v.y; b.z = (__bf16)v.z; b.w = (__bf16)v.w;
    *(bf16x4*)&hbuf[0][row][c4 * 4] = b;
  }

  // persistent B fragments: 4 ksteps x 4 gates x 16B = 64 regs
  bf16x8 Bf[4][4];
  {
    const bf16x8* wp8 = (const bf16x8*)Wp;
#pragma unroll
    for (int q = 0; q < 4; ++q)
#pragma unroll
      for (int ks = 0; ks < 4; ++ks)
        Bf[ks][q] = wp8[(wv * 16 + q * 4 + ks) * 64 + lane];
  }

  float bias_v[4], wx0_v[4], wx1_v[4];
#pragma unroll
  for (int q = 0; q < 4; ++q) {
    int n = wv * 64 + q * 16 + cn;
    bias_v[q] = biasp[n];
    wx0_v[q] = wx0p[n];
    wx1_v[q] = wx1p[n];
  }

  // c state: tile s, rows m = s*16 + quad*4 + r, unit junit — fp32 in regs
  float cc[2][4];
#pragma unroll
  for (int s = 0; s < 2; ++s)
#pragma unroll
    for (int r = 0; r < 4; ++r)
      cc[s][r] = c0[(bbase + s * 16 + quad * 4 + r) * HID + junit];

  __syncthreads();

  int cur = 0;
#pragma unroll 1
  for (int t = 0; t < OBS_T - 1; ++t) {
    f32x4 acc[2][4];
#pragma unroll
    for (int s = 0; s < 2; ++s)
#pragma unroll
      for (int r = 0; r < 4; ++r) {
        float2 ob = *(const float2*)&obs_s[t][s * 16 + quad * 4 + r][0];
#pragma unroll
        for (int q = 0; q < 4; ++q)
          acc[s][q][r] = fmaf(ob.y, wx1_v[q], fmaf(ob.x, wx0_v[q], bias_v[q]));
      }

    // gates += h @ W_hh^T  (2 tiles x 16 MFMAs), A loaded per-kstep
#pragma unroll
    for (int ks = 0; ks < 4; ++ks) {
      bf16x8 Av0 = *(const bf16x8*)&hbuf[cur][cn][ks * 32 + quad * 8];
      bf16x8 Av1 = *(const bf16x8*)&hbuf[cur][16 + cn][ks * 32 + quad * 8];
#pragma unroll
      for (int q = 0; q < 4; ++q) {
        acc[0][q] = __builtin_amdgcn_mfma_f32_16x16x32_bf16(Av0, Bf[ks][q], acc[0][q], 0, 0, 0);
        acc[1][q] = __builtin_amdgcn_mfma_f32_16x16x32_bf16(Av1, Bf[ks][q], acc[1][q], 0, 0, 0);
      }
    }

    const int nxt = cur ^ 1;
#pragma unroll
    for (int s = 0; s < 2; ++s)
#pragma unroll
      for (int r = 0; r < 4; ++r) {
        float h = cell_update(acc[s][0][r], acc[s][1][r], acc[s][2][r], acc[s][3][r],
                              cc[s][r]);
        hbuf[nxt][s * 16 + quad * 4 + r][junit] = (__bf16)h;
      }
    __syncthreads();
    cur = nxt;
  }

  // peeled final step: h goes straight to global
  {
    const int t = OBS_T - 1;
    f32x4 acc[2][4];
#pragma unroll
    for (int s = 0; s < 2; ++s)
#pragma unroll
      for (int r = 0; r < 4; ++r) {
        float2 ob = *(const float2*)&obs_s[t][s * 16 + quad * 4 + r][0];
#pragma unroll
        for (int q = 0; q < 4; ++q)
          acc[s][q][r] = fmaf(ob.y, wx1_v[q], fmaf(ob.x, wx0_v[q], bias_v[q]));
      }
#pragma unroll
    for (int ks = 0; ks < 4; ++ks) {
      bf16x8 Av0 = *(const bf16x8*)&hbuf[cur][cn][ks * 32 + quad * 8];
      bf16x8 Av1 = *(const bf16x8*)&hbuf[cur][16 + cn][ks * 32 + quad * 8];
#pragma unroll
      for (int q = 0; q < 4; ++q) {
        acc[0][q] = __builtin_amdgcn_mfma_f32_16x16x32_bf16(Av0, Bf[ks][q], acc[0][q], 0, 0, 0);
        acc[1][q] = __builtin_amdgcn_mfma_f32_16x16x32_bf16(Av1, Bf[ks][q], acc[1][q], 0, 0, 0);
      }
    }
#pragma unroll
    for (int s = 0; s < 2; ++s)
#pragma unroll
      for (int r = 0; r < 4; ++r) {
        float h = cell_update(acc[s][0][r], acc[s][1][r], acc[s][2][r], acc[s][3][r],
                              cc[s][r]);
        out[(bbase + s * 16 + quad * 4 + r) * HID + junit] = h;
      }
  }
}

extern "C" void kernel_launch(void* const* d_in, const int* in_sizes, int n_in,
                              void* d_out, int out_size, void* d_ws, size_t ws_size,
                              hipStream_t stream) {
  const float* obs = (const float*)d_in[0];
  const float* h0 = (const float*)d_in[1];
  const float* c0 = (const float*)d_in[2];
  const float* W_emb = (const float*)d_in[3];
  const float* b_emb = (const float*)d_in[4];
  const float* W_ih = (const float*)d_in[5];
  const float* W_hh = (const float*)d_in[6];
  const float* b_ih = (const float*)d_in[7];
  const float* b_hh = (const float*)d_in[8];
  float* out = (float*)d_out;
  const int batch = in_sizes[1] / HID;

  __bf16* Wp = (__bf16*)d_ws;                     // 65536 bf16 = 128 KB
  float* biasp = (float*)((char*)d_ws + 131072);  // 3 x 512 f32
  float* wx0p = biasp + NGATE;
  float* wx1p = wx0p + NGATE;

  prep_vec<<<2, 256, 0, stream>>>(W_emb, b_emb, W_ih, b_ih, b_hh, biasp, wx0p, wx1p);
  prep_wp<<<256, 256, 0, stream>>>(W_hh, Wp);
  lstm_fused<<<batch / MB, 512, 0, stream>>>(obs, h0, c0, Wp, biasp, wx0p, wx1p, out, batch);
}